// Round 1
// baseline (651.287 us; speedup 1.0000x reference)
//
#include <hip/hip_runtime.h>
#include <math.h>

#define BATCH 32
#define DIN   2048
#define DK    128
#define NREPS 400000
#define ACT   7
#define NGRP2 3125               /* groups of 128 rows, exact: 400000/128 */
#define GBLK  768                /* 3 blocks/CU x 256 CU */

__device__ __forceinline__ void topk_insert(float s, int n,
    float& d0, float& d1, float& d2, float& d3, float& d4,
    int& i0, int& i1, int& i2, int& i3, int& i4)
{
    if (s < d4) {
        if (s < d3) {
            d4 = d3; i4 = i3;
            if (s < d2) {
                d3 = d2; i3 = i2;
                if (s < d1) {
                    d2 = d1; i2 = i1;
                    if (s < d0) { d1 = d0; i1 = i0; d0 = s; i0 = n; }
                    else        { d1 = s;  i1 = n; }
                } else { d2 = s; i2 = n; }
            } else { d3 = s; i3 = n; }
        } else { d4 = s; i4 = n; }
    }
}

// ---------------------------------------------------------------------------
// Kernel 1: batch_rep = x @ W_enc + b_enc. Writes brep_t[k][b] = -2*br[b][k]
// (k-major, pre-scaled) and brnorm[b] = ||br_b||^2. Also zeroes the dynamic
// group counter for kernel 2 (re-zeroed every launch -> graph-replay safe).
// ---------------------------------------------------------------------------
__global__ __launch_bounds__(256) void encoder_kernel(
    const float* __restrict__ x, const float* __restrict__ W,
    const float* __restrict__ be, float* __restrict__ brept,
    float* __restrict__ brnorm, int* __restrict__ cnt)
{
    __shared__ float xs[DIN];
    __shared__ float part[256];
    __shared__ float vrow[DK];
    const int b = blockIdx.x, t = threadIdx.x;
    if (b == 0 && t == 0) *cnt = 0;

    const float4* x4 = (const float4*)(x + (size_t)b * DIN);
    float4* xs4 = (float4*)xs;
    xs4[t]       = x4[t];
    xs4[t + 256] = x4[t + 256];
    __syncthreads();

    const int d = t & 127, hh = t >> 7;
    const float* Wp = W + (size_t)(hh * 1024) * DK + d;
    const float* xp = xs + hh * 1024;
    float a0 = 0.f, a1 = 0.f, a2 = 0.f, a3 = 0.f;
    for (int i = 0; i < 1024; i += 8) {
        const float w0 = Wp[(size_t)i * DK];
        const float w1 = Wp[(size_t)(i + 1) * DK];
        const float w2 = Wp[(size_t)(i + 2) * DK];
        const float w3 = Wp[(size_t)(i + 3) * DK];
        const float w4 = Wp[(size_t)(i + 4) * DK];
        const float w5 = Wp[(size_t)(i + 5) * DK];
        const float w6 = Wp[(size_t)(i + 6) * DK];
        const float w7 = Wp[(size_t)(i + 7) * DK];
        a0 = fmaf(xp[i],     w0, a0);
        a1 = fmaf(xp[i + 1], w1, a1);
        a2 = fmaf(xp[i + 2], w2, a2);
        a3 = fmaf(xp[i + 3], w3, a3);
        a0 = fmaf(xp[i + 4], w4, a0);
        a1 = fmaf(xp[i + 5], w5, a1);
        a2 = fmaf(xp[i + 6], w6, a2);
        a3 = fmaf(xp[i + 7], w7, a3);
    }
    part[t] = (a0 + a1) + (a2 + a3);
    __syncthreads();
    if (t < DK) {
        float v = part[t] + part[t + 128] + be[t];
        brept[t * BATCH + b] = -2.0f * v;
        vrow[t] = v * v;
    }
    __syncthreads();
    if (t == 0) {
        float s = 0.f;
        for (int i = 0; i < DK; i++) s += vrow[i];
        brnorm[b] = s;
    }
}

// ---------------------------------------------------------------------------
// Kernel 2: lane-per-2-rows streaming distance + per-wave top-5.
// brt staged in LDS (16 KB) and read as broadcast ds_read_b128: one b128
// (4 b-values at one k) feeds 8 FMAs (2 rows x 4 components). Each wave
// grabs one 128-row group from a global atomic counter (load-balanced).
// Scatter/scan over the stride-36 slab runs twice (row-pass 0, row-pass 1).
// ---------------------------------------------------------------------------
#define FMA4(Acc, S) \
    Acc.x = fmaf(p0.x, S.x, Acc.x); Acc.x = fmaf(p1.x, S.y, Acc.x); \
    Acc.x = fmaf(p2.x, S.z, Acc.x); Acc.x = fmaf(p3.x, S.w, Acc.x); \
    Acc.y = fmaf(p0.y, S.x, Acc.y); Acc.y = fmaf(p1.y, S.y, Acc.y); \
    Acc.y = fmaf(p2.y, S.z, Acc.y); Acc.y = fmaf(p3.y, S.w, Acc.y); \
    Acc.z = fmaf(p0.z, S.x, Acc.z); Acc.z = fmaf(p1.z, S.y, Acc.z); \
    Acc.z = fmaf(p2.z, S.z, Acc.z); Acc.z = fmaf(p3.z, S.w, Acc.z); \
    Acc.w = fmaf(p0.w, S.x, Acc.w); Acc.w = fmaf(p1.w, S.y, Acc.w); \
    Acc.w = fmaf(p2.w, S.z, Acc.w); Acc.w = fmaf(p3.w, S.w, Acc.w);

__global__ __launch_bounds__(256, 3) void dist_topk_kernel(
    const float* __restrict__ reps, const float* __restrict__ brt,
    float* __restrict__ pd, int* __restrict__ pi, int* __restrict__ cnt)
{
    __shared__ float sbrt[DK * BATCH];     // 16 KB, [k][b]
    __shared__ float wdist[4 * 64 * 36];   // 36 KB, per-wave slabs
    const int t = threadIdx.x, blk = blockIdx.x;
    const int wid = t >> 6, ln = t & 63;
    const int b = ln & 31, h = ln >> 5;
    float* wd = wdist + wid * (64 * 36);

    {   // stage brt -> LDS, coalesced float4 (4096 floats / 256 threads)
        const float4* bsrc = (const float4*)brt;
        float4* bdst = (float4*)sbrt;
        #pragma unroll
        for (int i = 0; i < 4; i++) bdst[t + 256 * i] = bsrc[t + 256 * i];
    }
    __syncthreads();

    float d0 = 3.0e38f, d1 = 3.0e38f, d2 = 3.0e38f, d3 = 3.0e38f, d4 = 3.0e38f;
    int   i0 = 0, i1 = 0, i2 = 0, i3 = 0, i4 = 0;

    const float4* sb4 = (const float4*)sbrt;

    for (;;) {
        int g = 0;
        if (ln == 0) g = atomicAdd(cnt, 1);
        g = __shfl(g, 0);
        if (g >= NGRP2) break;

        const float4* rp0 = (const float4*)(reps + (size_t)(g * 128 + ln) * DK);
        const float4* rp1 = rp0 + 64 * (DK / 4);   // row + 64

        float4 a0[8], a1[8];
        #pragma unroll
        for (int q = 0; q < 8; q++) {
            a0[q] = make_float4(0.f, 0.f, 0.f, 0.f);
            a1[q] = make_float4(0.f, 0.f, 0.f, 0.f);
        }
        float n0 = 0.f, n1 = 0.f;

        #pragma unroll 1
        for (int c = 0; c < 8; c++) {              // 8 chunks of 16 k
            float4 r0[4], r1[4];
            #pragma unroll
            for (int q = 0; q < 4; q++) { r0[q] = rp0[c * 4 + q]; r1[q] = rp1[c * 4 + q]; }
            #pragma unroll
            for (int q = 0; q < 4; q++) {
                const float4 s0 = r0[q], s1 = r1[q];
                n0 = fmaf(s0.x, s0.x, n0); n0 = fmaf(s0.y, s0.y, n0);
                n0 = fmaf(s0.z, s0.z, n0); n0 = fmaf(s0.w, s0.w, n0);
                n1 = fmaf(s1.x, s1.x, n1); n1 = fmaf(s1.y, s1.y, n1);
                n1 = fmaf(s1.z, s1.z, n1); n1 = fmaf(s1.w, s1.w, n1);
                const float4* pb = sb4 + (c * 16 + q * 4) * 8;   // k-row base
                #pragma unroll
                for (int j = 0; j < 8; j++) {
                    const float4 p0 = pb[j], p1 = pb[j + 8], p2 = pb[j + 16], p3 = pb[j + 24];
                    float4 A = a0[j];
                    FMA4(A, s0)
                    a0[j] = A;
                    float4 B = a1[j];
                    FMA4(B, s1)
                    a1[j] = B;
                }
            }
        }

        // ---- pass 0: rows g*128 + 0..63 (lane ln's row0 at slab row ln)
        #pragma unroll
        for (int q = 0; q < 8; q++) {
            float4 v = a0[q];
            v.x += n0; v.y += n0; v.z += n0; v.w += n0;
            *(float4*)&wd[ln * 36 + 4 * q] = v;
        }
        asm volatile("s_waitcnt lgkmcnt(0)" ::: "memory");
        {
            const int nb = g * 128;
            #pragma unroll 4
            for (int s = 0; s < 32; s++) {
                const int row = h * 32 + s;
                topk_insert(wd[row * 36 + b], nb + row, d0, d1, d2, d3, d4, i0, i1, i2, i3, i4);
            }
        }
        asm volatile("s_waitcnt lgkmcnt(0)" ::: "memory");

        // ---- pass 1: rows g*128 + 64..127
        #pragma unroll
        for (int q = 0; q < 8; q++) {
            float4 v = a1[q];
            v.x += n1; v.y += n1; v.z += n1; v.w += n1;
            *(float4*)&wd[ln * 36 + 4 * q] = v;
        }
        asm volatile("s_waitcnt lgkmcnt(0)" ::: "memory");
        {
            const int nb = g * 128 + 64;
            #pragma unroll 4
            for (int s = 0; s < 32; s++) {
                const int row = h * 32 + s;
                topk_insert(wd[row * 36 + b], nb + row, d0, d1, d2, d3, d4, i0, i1, i2, i3, i4);
            }
        }
        asm volatile("s_waitcnt lgkmcnt(0)" ::: "memory");
    }

    // ---- block merge: 8 lists (4 waves x 2 halves) per batch row
    __syncthreads();
    float* cD = wdist;                 // 256*5 = 1280 f
    int*   cI = (int*)(wdist + 1280);  // 1280 i
    {
        const int base = t * 5;
        cD[base]     = d0; cI[base]     = i0;
        cD[base + 1] = d1; cI[base + 1] = i1;
        cD[base + 2] = d2; cI[base + 2] = i2;
        cD[base + 3] = d3; cI[base + 3] = i3;
        cD[base + 4] = d4; cI[base + 4] = i4;
    }
    __syncthreads();
    if (t < 32) {
        float e0 = 3.0e38f, e1 = 3.0e38f, e2 = 3.0e38f, e3 = 3.0e38f, e4 = 3.0e38f;
        int   j0 = 0, j1 = 0, j2 = 0, j3 = 0, j4 = 0;
        for (int j = 0; j < 8; j++) {
            const int base = (t + 32 * j) * 5;
            #pragma unroll
            for (int e = 0; e < 5; e++)
                topk_insert(cD[base + e], cI[base + e],
                            e0, e1, e2, e3, e4, j0, j1, j2, j3, j4);
        }
        const int ob = (blk * BATCH + t) * 5;
        pd[ob] = e0; pd[ob + 1] = e1; pd[ob + 2] = e2; pd[ob + 3] = e3; pd[ob + 4] = e4;
        pi[ob] = j0; pi[ob + 1] = j1; pi[ob + 2] = j2; pi[ob + 3] = j3; pi[ob + 4] = j4;
    }
}

// ---------------------------------------------------------------------------
// Kernel 3: merge G partial lists per b, softmax(-dist), gather actions.
// ---------------------------------------------------------------------------
__global__ __launch_bounds__(256) void final_kernel(
    const float* __restrict__ pd, const int* __restrict__ pi,
    const float* __restrict__ brnorm, const float* __restrict__ actions,
    float* __restrict__ out, int G)
{
    __shared__ float lD[256 * 5];
    __shared__ int   lI[256 * 5];
    __shared__ float sD[32 * 5];
    __shared__ int   sI[32 * 5];
    const int b = blockIdx.x, t = threadIdx.x;

    float d0 = 3.0e38f, d1 = 3.0e38f, d2 = 3.0e38f, d3 = 3.0e38f, d4 = 3.0e38f;
    int   i0 = 0, i1 = 0, i2 = 0, i3 = 0, i4 = 0;
    for (int g = t; g < G; g += 256) {
        const int base = (g * BATCH + b) * 5;
        #pragma unroll
        for (int e = 0; e < 5; e++)
            topk_insert(pd[base + e], pi[base + e],
                        d0, d1, d2, d3, d4, i0, i1, i2, i3, i4);
    }
    lD[t * 5] = d0; lD[t * 5 + 1] = d1; lD[t * 5 + 2] = d2; lD[t * 5 + 3] = d3; lD[t * 5 + 4] = d4;
    lI[t * 5] = i0; lI[t * 5 + 1] = i1; lI[t * 5 + 2] = i2; lI[t * 5 + 3] = i3; lI[t * 5 + 4] = i4;
    __syncthreads();
    if (t < 32) {
        d0 = d1 = d2 = d3 = d4 = 3.0e38f; i0 = i1 = i2 = i3 = i4 = 0;
        for (int s = 0; s < 8; s++) {
            const int base = (t * 8 + s) * 5;
            #pragma unroll
            for (int e = 0; e < 5; e++)
                topk_insert(lD[base + e], lI[base + e],
                            d0, d1, d2, d3, d4, i0, i1, i2, i3, i4);
        }
        sD[t * 5] = d0; sD[t * 5 + 1] = d1; sD[t * 5 + 2] = d2; sD[t * 5 + 3] = d3; sD[t * 5 + 4] = d4;
        sI[t * 5] = i0; sI[t * 5 + 1] = i1; sI[t * 5 + 2] = i2; sI[t * 5 + 3] = i3; sI[t * 5 + 4] = i4;
    }
    __syncthreads();
    if (t == 0) {
        d0 = d1 = d2 = d3 = d4 = 3.0e38f; i0 = i1 = i2 = i3 = i4 = 0;
        for (int s = 0; s < 32; s++) {
            const int base = s * 5;
            #pragma unroll
            for (int e = 0; e < 5; e++)
                topk_insert(sD[base + e], sI[base + e],
                            d0, d1, d2, d3, d4, i0, i1, i2, i3, i4);
        }
        const float bn = brnorm[b];
        float dist[5]; int idx[5];
        dist[0] = d0; dist[1] = d1; dist[2] = d2; dist[3] = d3; dist[4] = d4;
        idx[0] = i0; idx[1] = i1; idx[2] = i2; idx[3] = i3; idx[4] = i4;
        float dmin = 3.0e38f;
        #pragma unroll
        for (int e = 0; e < 5; e++) {
            dist[e] = sqrtf(fmaxf(dist[e] + bn, 1e-12f));
            dmin = fminf(dmin, dist[e]);
        }
        float w[5], wsum = 0.f;
        #pragma unroll
        for (int e = 0; e < 5; e++) { w[e] = expf(dmin - dist[e]); wsum += w[e]; }
        const float inv = 1.0f / wsum;
        for (int a = 0; a < ACT; a++) {
            float o = 0.f;
            #pragma unroll
            for (int e = 0; e < 5; e++)
                o = fmaf(w[e], actions[(size_t)idx[e] * ACT + a], o);
            out[b * ACT + a] = o * inv;
        }
    }
}

extern "C" void kernel_launch(void* const* d_in, const int* in_sizes, int n_in,
                              void* d_out, int out_size, void* d_ws, size_t ws_size,
                              hipStream_t stream)
{
    (void)in_sizes; (void)n_in; (void)out_size;
    const float* x       = (const float*)d_in[0];
    const float* W       = (const float*)d_in[1];
    const float* be      = (const float*)d_in[2];
    const float* reps    = (const float*)d_in[3];
    const float* actions = (const float*)d_in[4];
    // d_in[5] = k (always 5; structural)

    float* ws     = (float*)d_ws;
    float* brept  = ws;            // 4096 floats (brep_t[k][b], pre-scaled -2)
    float* brnorm = ws + 4096;     // 32 floats
    int*   cnt    = (int*)(ws + 4128);  // dynamic group counter
    float* pd     = ws + 4160;     // G*32*5 floats

    int G = GBLK;                  // 768 = 3 blocks/CU exactly; waves grab
                                   // groups dynamically so any G is correct
    {
        const size_t avail_f = ws_size / 4;
        if (avail_f < 4160 + (size_t)G * 320) {
            long fit = ((long)avail_f - 4160) / 320;
            G = (fit < 1) ? 1 : (int)fit;
            if (G > GBLK) G = GBLK;
        }
    }
    int* pi = (int*)(pd + (size_t)G * BATCH * 5);

    encoder_kernel  <<<32, 256, 0, stream>>>(x, W, be, brept, brnorm, cnt);
    dist_topk_kernel<<<G,  256, 0, stream>>>(reps, brept, pd, pi, cnt);
    final_kernel    <<<32, 256, 0, stream>>>(pd, pi, brnorm, actions, (float*)d_out, G);
}

// Round 2
// 635.725 us; speedup vs baseline: 1.0245x; 1.0245x over previous
//
#include <hip/hip_runtime.h>
#include <math.h>

#define BATCH 32
#define DIN   2048
#define DK    128
#define NREPS 400000
#define ACT   7
#define NGRP2 3125               /* groups of 128 rows, exact: 400000/128 */
#define GBLK  768                /* 3 blocks/CU x 256 CU */

__device__ __forceinline__ void topk_insert(float s, int n,
    float& d0, float& d1, float& d2, float& d3, float& d4,
    int& i0, int& i1, int& i2, int& i3, int& i4)
{
    if (s < d4) {
        if (s < d3) {
            d4 = d3; i4 = i3;
            if (s < d2) {
                d3 = d2; i3 = i2;
                if (s < d1) {
                    d2 = d1; i2 = i1;
                    if (s < d0) { d1 = d0; i1 = i0; d0 = s; i0 = n; }
                    else        { d1 = s;  i1 = n; }
                } else { d2 = s; i2 = n; }
            } else { d3 = s; i3 = n; }
        } else { d4 = s; i4 = n; }
    }
}

// ---------------------------------------------------------------------------
// Kernel 1: batch_rep = x @ W_enc + b_enc. Writes brep_t[k][b] = -2*br[b][k]
// (k-major, pre-scaled) and brnorm[b] = ||br_b||^2. Also zeroes the dynamic
// group counter for kernel 2 (re-zeroed every launch -> graph-replay safe).
// ---------------------------------------------------------------------------
__global__ __launch_bounds__(256) void encoder_kernel(
    const float* __restrict__ x, const float* __restrict__ W,
    const float* __restrict__ be, float* __restrict__ brept,
    float* __restrict__ brnorm, int* __restrict__ cnt)
{
    __shared__ float xs[DIN];
    __shared__ float part[256];
    __shared__ float vrow[DK];
    const int b = blockIdx.x, t = threadIdx.x;
    if (b == 0 && t == 0) *cnt = 0;

    const float4* x4 = (const float4*)(x + (size_t)b * DIN);
    float4* xs4 = (float4*)xs;
    xs4[t]       = x4[t];
    xs4[t + 256] = x4[t + 256];
    __syncthreads();

    const int d = t & 127, hh = t >> 7;
    const float* Wp = W + (size_t)(hh * 1024) * DK + d;
    const float* xp = xs + hh * 1024;
    float a0 = 0.f, a1 = 0.f, a2 = 0.f, a3 = 0.f;
    for (int i = 0; i < 1024; i += 8) {
        const float w0 = Wp[(size_t)i * DK];
        const float w1 = Wp[(size_t)(i + 1) * DK];
        const float w2 = Wp[(size_t)(i + 2) * DK];
        const float w3 = Wp[(size_t)(i + 3) * DK];
        const float w4 = Wp[(size_t)(i + 4) * DK];
        const float w5 = Wp[(size_t)(i + 5) * DK];
        const float w6 = Wp[(size_t)(i + 6) * DK];
        const float w7 = Wp[(size_t)(i + 7) * DK];
        a0 = fmaf(xp[i],     w0, a0);
        a1 = fmaf(xp[i + 1], w1, a1);
        a2 = fmaf(xp[i + 2], w2, a2);
        a3 = fmaf(xp[i + 3], w3, a3);
        a0 = fmaf(xp[i + 4], w4, a0);
        a1 = fmaf(xp[i + 5], w5, a1);
        a2 = fmaf(xp[i + 6], w6, a2);
        a3 = fmaf(xp[i + 7], w7, a3);
    }
    part[t] = (a0 + a1) + (a2 + a3);
    __syncthreads();
    if (t < DK) {
        float v = part[t] + part[t + 128] + be[t];
        brept[t * BATCH + b] = -2.0f * v;
        vrow[t] = v * v;
    }
    __syncthreads();
    if (t == 0) {
        float s = 0.f;
        for (int i = 0; i < DK; i++) s += vrow[i];
        brnorm[b] = s;
    }
}

// ---------------------------------------------------------------------------
// Kernel 2: lane-per-2-rows streaming distance + per-wave top-5.
// brt staged in LDS (16 KB), read as broadcast ds_read_b128 (one b128 = 4
// b-values at one k feeds 8 FMAs: 2 rows x 4 b). Reps are streamed as FULL
// 128-B cache lines per row per superchunk (8 contiguous float4 issued
// back-to-back -> both line halves coalesce in MSHRs; this is the pattern
// that kept FETCH at ~108 MB in the 207us kernel. 16-k chunking fetched
// half-lines twice and blew FETCH to 700 MB). k-order of FMAs identical to
// the verified kernel -> bit-exact distances. Dynamic atomic group grab.
// ---------------------------------------------------------------------------
#define FMA4(Acc, S) \
    Acc.x = fmaf(p0.x, S.x, Acc.x); Acc.x = fmaf(p1.x, S.y, Acc.x); \
    Acc.x = fmaf(p2.x, S.z, Acc.x); Acc.x = fmaf(p3.x, S.w, Acc.x); \
    Acc.y = fmaf(p0.y, S.x, Acc.y); Acc.y = fmaf(p1.y, S.y, Acc.y); \
    Acc.y = fmaf(p2.y, S.z, Acc.y); Acc.y = fmaf(p3.y, S.w, Acc.y); \
    Acc.z = fmaf(p0.z, S.x, Acc.z); Acc.z = fmaf(p1.z, S.y, Acc.z); \
    Acc.z = fmaf(p2.z, S.z, Acc.z); Acc.z = fmaf(p3.z, S.w, Acc.z); \
    Acc.w = fmaf(p0.w, S.x, Acc.w); Acc.w = fmaf(p1.w, S.y, Acc.w); \
    Acc.w = fmaf(p2.w, S.z, Acc.w); Acc.w = fmaf(p3.w, S.w, Acc.w);

__global__ __launch_bounds__(256, 3) void dist_topk_kernel(
    const float* __restrict__ reps, const float* __restrict__ brt,
    float* __restrict__ pd, int* __restrict__ pi, int* __restrict__ cnt)
{
    __shared__ float sbrt[DK * BATCH];     // 16 KB, [k][b]
    __shared__ float wdist[4 * 64 * 36];   // 36 KB, per-wave slabs
    const int t = threadIdx.x, blk = blockIdx.x;
    const int wid = t >> 6, ln = t & 63;
    const int b = ln & 31, h = ln >> 5;
    float* wd = wdist + wid * (64 * 36);

    {   // stage brt -> LDS, coalesced float4 (4096 floats / 256 threads)
        const float4* bsrc = (const float4*)brt;
        float4* bdst = (float4*)sbrt;
        #pragma unroll
        for (int i = 0; i < 4; i++) bdst[t + 256 * i] = bsrc[t + 256 * i];
    }
    __syncthreads();

    float d0 = 3.0e38f, d1 = 3.0e38f, d2 = 3.0e38f, d3 = 3.0e38f, d4 = 3.0e38f;
    int   i0 = 0, i1 = 0, i2 = 0, i3 = 0, i4 = 0;

    const float4* sb4 = (const float4*)sbrt;

    for (;;) {
        int g = 0;
        if (ln == 0) g = atomicAdd(cnt, 1);
        g = __shfl(g, 0);
        if (g >= NGRP2) break;

        const float4* rp0 = (const float4*)(reps + (size_t)(g * 128 + ln) * DK);
        const float4* rp1 = rp0 + 64 * (DK / 4);   // row + 64

        float4 a0[8], a1[8];
        #pragma unroll
        for (int q = 0; q < 8; q++) {
            a0[q] = make_float4(0.f, 0.f, 0.f, 0.f);
            a1[q] = make_float4(0.f, 0.f, 0.f, 0.f);
        }
        float n0 = 0.f, n1 = 0.f;

        #pragma unroll 1
        for (int c = 0; c < 4; c++) {              // 4 superchunks of 32 k
            // full 128-B line per row, issued back-to-back
            float4 r0[8], r1[8];
            #pragma unroll
            for (int q = 0; q < 8; q++) r0[q] = rp0[c * 8 + q];
            #pragma unroll
            for (int q = 0; q < 8; q++) r1[q] = rp1[c * 8 + q];
            #pragma unroll
            for (int q = 0; q < 8; q++) {
                const float4 s0 = r0[q], s1 = r1[q];
                n0 = fmaf(s0.x, s0.x, n0); n0 = fmaf(s0.y, s0.y, n0);
                n0 = fmaf(s0.z, s0.z, n0); n0 = fmaf(s0.w, s0.w, n0);
                n1 = fmaf(s1.x, s1.x, n1); n1 = fmaf(s1.y, s1.y, n1);
                n1 = fmaf(s1.z, s1.z, n1); n1 = fmaf(s1.w, s1.w, n1);
                const float4* pb = sb4 + (c * 32 + q * 4) * 8;   // k-row base
                #pragma unroll
                for (int j = 0; j < 8; j++) {
                    const float4 p0 = pb[j], p1 = pb[j + 8], p2 = pb[j + 16], p3 = pb[j + 24];
                    float4 A = a0[j];
                    FMA4(A, s0)
                    a0[j] = A;
                    float4 B = a1[j];
                    FMA4(B, s1)
                    a1[j] = B;
                }
            }
        }

        // ---- pass 0: rows g*128 + 0..63 (lane ln's row0 at slab row ln)
        #pragma unroll
        for (int q = 0; q < 8; q++) {
            float4 v = a0[q];
            v.x += n0; v.y += n0; v.z += n0; v.w += n0;
            *(float4*)&wd[ln * 36 + 4 * q] = v;
        }
        asm volatile("s_waitcnt lgkmcnt(0)" ::: "memory");
        {
            const int nb = g * 128;
            #pragma unroll 4
            for (int s = 0; s < 32; s++) {
                const int row = h * 32 + s;
                topk_insert(wd[row * 36 + b], nb + row, d0, d1, d2, d3, d4, i0, i1, i2, i3, i4);
            }
        }
        asm volatile("s_waitcnt lgkmcnt(0)" ::: "memory");

        // ---- pass 1: rows g*128 + 64..127
        #pragma unroll
        for (int q = 0; q < 8; q++) {
            float4 v = a1[q];
            v.x += n1; v.y += n1; v.z += n1; v.w += n1;
            *(float4*)&wd[ln * 36 + 4 * q] = v;
        }
        asm volatile("s_waitcnt lgkmcnt(0)" ::: "memory");
        {
            const int nb = g * 128 + 64;
            #pragma unroll 4
            for (int s = 0; s < 32; s++) {
                const int row = h * 32 + s;
                topk_insert(wd[row * 36 + b], nb + row, d0, d1, d2, d3, d4, i0, i1, i2, i3, i4);
            }
        }
        asm volatile("s_waitcnt lgkmcnt(0)" ::: "memory");
    }

    // ---- block merge: 8 lists (4 waves x 2 halves) per batch row
    __syncthreads();
    float* cD = wdist;                 // 256*5 = 1280 f
    int*   cI = (int*)(wdist + 1280);  // 1280 i
    {
        const int base = t * 5;
        cD[base]     = d0; cI[base]     = i0;
        cD[base + 1] = d1; cI[base + 1] = i1;
        cD[base + 2] = d2; cI[base + 2] = i2;
        cD[base + 3] = d3; cI[base + 3] = i3;
        cD[base + 4] = d4; cI[base + 4] = i4;
    }
    __syncthreads();
    if (t < 32) {
        float e0 = 3.0e38f, e1 = 3.0e38f, e2 = 3.0e38f, e3 = 3.0e38f, e4 = 3.0e38f;
        int   j0 = 0, j1 = 0, j2 = 0, j3 = 0, j4 = 0;
        for (int j = 0; j < 8; j++) {
            const int base = (t + 32 * j) * 5;
            #pragma unroll
            for (int e = 0; e < 5; e++)
                topk_insert(cD[base + e], cI[base + e],
                            e0, e1, e2, e3, e4, j0, j1, j2, j3, j4);
        }
        const int ob = (blk * BATCH + t) * 5;
        pd[ob] = e0; pd[ob + 1] = e1; pd[ob + 2] = e2; pd[ob + 3] = e3; pd[ob + 4] = e4;
        pi[ob] = j0; pi[ob + 1] = j1; pi[ob + 2] = j2; pi[ob + 3] = j3; pi[ob + 4] = j4;
    }
}

// ---------------------------------------------------------------------------
// Kernel 3: merge G partial lists per b, softmax(-dist), gather actions.
// ---------------------------------------------------------------------------
__global__ __launch_bounds__(256) void final_kernel(
    const float* __restrict__ pd, const int* __restrict__ pi,
    const float* __restrict__ brnorm, const float* __restrict__ actions,
    float* __restrict__ out, int G)
{
    __shared__ float lD[256 * 5];
    __shared__ int   lI[256 * 5];
    __shared__ float sD[32 * 5];
    __shared__ int   sI[32 * 5];
    const int b = blockIdx.x, t = threadIdx.x;

    float d0 = 3.0e38f, d1 = 3.0e38f, d2 = 3.0e38f, d3 = 3.0e38f, d4 = 3.0e38f;
    int   i0 = 0, i1 = 0, i2 = 0, i3 = 0, i4 = 0;
    for (int g = t; g < G; g += 256) {
        const int base = (g * BATCH + b) * 5;
        #pragma unroll
        for (int e = 0; e < 5; e++)
            topk_insert(pd[base + e], pi[base + e],
                        d0, d1, d2, d3, d4, i0, i1, i2, i3, i4);
    }
    lD[t * 5] = d0; lD[t * 5 + 1] = d1; lD[t * 5 + 2] = d2; lD[t * 5 + 3] = d3; lD[t * 5 + 4] = d4;
    lI[t * 5] = i0; lI[t * 5 + 1] = i1; lI[t * 5 + 2] = i2; lI[t * 5 + 3] = i3; lI[t * 5 + 4] = i4;
    __syncthreads();
    if (t < 32) {
        d0 = d1 = d2 = d3 = d4 = 3.0e38f; i0 = i1 = i2 = i3 = i4 = 0;
        for (int s = 0; s < 8; s++) {
            const int base = (t * 8 + s) * 5;
            #pragma unroll
            for (int e = 0; e < 5; e++)
                topk_insert(lD[base + e], lI[base + e],
                            d0, d1, d2, d3, d4, i0, i1, i2, i3, i4);
        }
        sD[t * 5] = d0; sD[t * 5 + 1] = d1; sD[t * 5 + 2] = d2; sD[t * 5 + 3] = d3; sD[t * 5 + 4] = d4;
        sI[t * 5] = i0; sI[t * 5 + 1] = i1; sI[t * 5 + 2] = i2; sI[t * 5 + 3] = i3; sI[t * 5 + 4] = i4;
    }
    __syncthreads();
    if (t == 0) {
        d0 = d1 = d2 = d3 = d4 = 3.0e38f; i0 = i1 = i2 = i3 = i4 = 0;
        for (int s = 0; s < 32; s++) {
            const int base = s * 5;
            #pragma unroll
            for (int e = 0; e < 5; e++)
                topk_insert(sD[base + e], sI[base + e],
                            d0, d1, d2, d3, d4, i0, i1, i2, i3, i4);
        }
        const float bn = brnorm[b];
        float dist[5]; int idx[5];
        dist[0] = d0; dist[1] = d1; dist[2] = d2; dist[3] = d3; dist[4] = d4;
        idx[0] = i0; idx[1] = i1; idx[2] = i2; idx[3] = i3; idx[4] = i4;
        float dmin = 3.0e38f;
        #pragma unroll
        for (int e = 0; e < 5; e++) {
            dist[e] = sqrtf(fmaxf(dist[e] + bn, 1e-12f));
            dmin = fminf(dmin, dist[e]);
        }
        float w[5], wsum = 0.f;
        #pragma unroll
        for (int e = 0; e < 5; e++) { w[e] = expf(dmin - dist[e]); wsum += w[e]; }
        const float inv = 1.0f / wsum;
        for (int a = 0; a < ACT; a++) {
            float o = 0.f;
            #pragma unroll
            for (int e = 0; e < 5; e++)
                o = fmaf(w[e], actions[(size_t)idx[e] * ACT + a], o);
            out[b * ACT + a] = o * inv;
        }
    }
}

extern "C" void kernel_launch(void* const* d_in, const int* in_sizes, int n_in,
                              void* d_out, int out_size, void* d_ws, size_t ws_size,
                              hipStream_t stream)
{
    (void)in_sizes; (void)n_in; (void)out_size;
    const float* x       = (const float*)d_in[0];
    const float* W       = (const float*)d_in[1];
    const float* be      = (const float*)d_in[2];
    const float* reps    = (const float*)d_in[3];
    const float* actions = (const float*)d_in[4];
    // d_in[5] = k (always 5; structural)

    float* ws     = (float*)d_ws;
    float* brept  = ws;            // 4096 floats (brep_t[k][b], pre-scaled -2)
    float* brnorm = ws + 4096;     // 32 floats
    int*   cnt    = (int*)(ws + 4128);  // dynamic group counter
    float* pd     = ws + 4160;     // G*32*5 floats

    int G = GBLK;                  // 768 = 3 blocks/CU exactly; waves grab
                                   // groups dynamically so any G is correct
    {
        const size_t avail_f = ws_size / 4;
        if (avail_f < 4160 + (size_t)G * 320) {
            long fit = ((long)avail_f - 4160) / 320;
            G = (fit < 1) ? 1 : (int)fit;
            if (G > GBLK) G = GBLK;
        }
    }
    int* pi = (int*)(pd + (size_t)G * BATCH * 5);

    encoder_kernel  <<<32, 256, 0, stream>>>(x, W, be, brept, brnorm, cnt);
    dist_topk_kernel<<<G,  256, 0, stream>>>(reps, brept, pd, pi, cnt);
    final_kernel    <<<32, 256, 0, stream>>>(pd, pi, brnorm, actions, (float*)d_out, G);
}

// Round 3
// 524.487 us; speedup vs baseline: 1.2418x; 1.2121x over previous
//
#include <hip/hip_runtime.h>
#include <math.h>

#define BATCH 32
#define DIN   2048
#define DK    128
#define NREPS 400000
#define ACT   7
#define NGRP2 3125               /* groups of 128 rows, exact: 400000/128 */
#define GBLK  768                /* 3 blocks/CU x 256 CU */

__device__ __forceinline__ void topk_insert(float s, int n,
    float& d0, float& d1, float& d2, float& d3, float& d4,
    int& i0, int& i1, int& i2, int& i3, int& i4)
{
    if (s < d4) {
        if (s < d3) {
            d4 = d3; i4 = i3;
            if (s < d2) {
                d3 = d2; i3 = i2;
                if (s < d1) {
                    d2 = d1; i2 = i1;
                    if (s < d0) { d1 = d0; i1 = i0; d0 = s; i0 = n; }
                    else        { d1 = s;  i1 = n; }
                } else { d2 = s; i2 = n; }
            } else { d3 = s; i3 = n; }
        } else { d4 = s; i4 = n; }
    }
}

// ---------------------------------------------------------------------------
// Kernel 1: batch_rep = x @ W_enc + b_enc. Writes brep_t[k][b] = -2*br[b][k]
// (k-major, pre-scaled) and brnorm[b] = ||br_b||^2. Also zeroes the dynamic
// group counter for kernel 2 (re-zeroed every launch -> graph-replay safe).
// ---------------------------------------------------------------------------
__global__ __launch_bounds__(256) void encoder_kernel(
    const float* __restrict__ x, const float* __restrict__ W,
    const float* __restrict__ be, float* __restrict__ brept,
    float* __restrict__ brnorm, int* __restrict__ cnt)
{
    __shared__ float xs[DIN];
    __shared__ float part[256];
    __shared__ float vrow[DK];
    const int b = blockIdx.x, t = threadIdx.x;
    if (b == 0 && t == 0) *cnt = 0;

    const float4* x4 = (const float4*)(x + (size_t)b * DIN);
    float4* xs4 = (float4*)xs;
    xs4[t]       = x4[t];
    xs4[t + 256] = x4[t + 256];
    __syncthreads();

    const int d = t & 127, hh = t >> 7;
    const float* Wp = W + (size_t)(hh * 1024) * DK + d;
    const float* xp = xs + hh * 1024;
    float a0 = 0.f, a1 = 0.f, a2 = 0.f, a3 = 0.f;
    for (int i = 0; i < 1024; i += 8) {
        const float w0 = Wp[(size_t)i * DK];
        const float w1 = Wp[(size_t)(i + 1) * DK];
        const float w2 = Wp[(size_t)(i + 2) * DK];
        const float w3 = Wp[(size_t)(i + 3) * DK];
        const float w4 = Wp[(size_t)(i + 4) * DK];
        const float w5 = Wp[(size_t)(i + 5) * DK];
        const float w6 = Wp[(size_t)(i + 6) * DK];
        const float w7 = Wp[(size_t)(i + 7) * DK];
        a0 = fmaf(xp[i],     w0, a0);
        a1 = fmaf(xp[i + 1], w1, a1);
        a2 = fmaf(xp[i + 2], w2, a2);
        a3 = fmaf(xp[i + 3], w3, a3);
        a0 = fmaf(xp[i + 4], w4, a0);
        a1 = fmaf(xp[i + 5], w5, a1);
        a2 = fmaf(xp[i + 6], w6, a2);
        a3 = fmaf(xp[i + 7], w7, a3);
    }
    part[t] = (a0 + a1) + (a2 + a3);
    __syncthreads();
    if (t < DK) {
        float v = part[t] + part[t + 128] + be[t];
        brept[t * BATCH + b] = -2.0f * v;
        vrow[t] = v * v;
    }
    __syncthreads();
    if (t == 0) {
        float s = 0.f;
        for (int i = 0; i < DK; i++) s += vrow[i];
        brnorm[b] = s;
    }
}

// ---------------------------------------------------------------------------
// Kernel 2: lane-per-2-rows streaming distance + per-wave top-5.
// b-operand: brt staged once in LDS (16 KB), inner loop reads it as
// broadcast ds_read_b128 (conflict-free); each b128 feeds 8 FMAs (2 rows x
// 4 b). Register discipline is the critical fix vs rounds 1-2: NO full-line
// register staging arrays (they pushed the working set to ~164 VGPRs ->
// compiler spilled at 84 -> 68 MB scratch writes, 600 MB FETCH, VALU 8%).
// Per-q software-pipelined float4 pairs keep the live set ~115 regs, and
// __launch_bounds__(256,2) gives the allocator a 256-VGPR budget.
// ---------------------------------------------------------------------------
#define FMA4(Acc, S) \
    Acc.x = fmaf(p0.x, S.x, Acc.x); Acc.x = fmaf(p1.x, S.y, Acc.x); \
    Acc.x = fmaf(p2.x, S.z, Acc.x); Acc.x = fmaf(p3.x, S.w, Acc.x); \
    Acc.y = fmaf(p0.y, S.x, Acc.y); Acc.y = fmaf(p1.y, S.y, Acc.y); \
    Acc.y = fmaf(p2.y, S.z, Acc.y); Acc.y = fmaf(p3.y, S.w, Acc.y); \
    Acc.z = fmaf(p0.z, S.x, Acc.z); Acc.z = fmaf(p1.z, S.y, Acc.z); \
    Acc.z = fmaf(p2.z, S.z, Acc.z); Acc.z = fmaf(p3.z, S.w, Acc.z); \
    Acc.w = fmaf(p0.w, S.x, Acc.w); Acc.w = fmaf(p1.w, S.y, Acc.w); \
    Acc.w = fmaf(p2.w, S.z, Acc.w); Acc.w = fmaf(p3.w, S.w, Acc.w);

__global__ __launch_bounds__(256, 2) void dist_topk_kernel(
    const float* __restrict__ reps, const float* __restrict__ brt,
    float* __restrict__ pd, int* __restrict__ pi, int* __restrict__ cnt)
{
    __shared__ float sbrt[DK * BATCH];     // 16 KB, [k][b]
    __shared__ float wdist[4 * 64 * 36];   // 36 KB, per-wave slabs
    const int t = threadIdx.x, blk = blockIdx.x;
    const int wid = t >> 6, ln = t & 63;
    const int b = ln & 31, h = ln >> 5;
    float* wd = wdist + wid * (64 * 36);

    {   // stage brt -> LDS, coalesced float4 (4096 floats / 256 threads)
        const float4* bsrc = (const float4*)brt;
        float4* bdst = (float4*)sbrt;
        #pragma unroll
        for (int i = 0; i < 4; i++) bdst[t + 256 * i] = bsrc[t + 256 * i];
    }
    __syncthreads();

    float d0 = 3.0e38f, d1 = 3.0e38f, d2 = 3.0e38f, d3 = 3.0e38f, d4 = 3.0e38f;
    int   i0 = 0, i1 = 0, i2 = 0, i3 = 0, i4 = 0;

    const float4* sb4 = (const float4*)sbrt;

    for (;;) {
        int g = 0;
        if (ln == 0) g = atomicAdd(cnt, 1);
        g = __shfl(g, 0);
        if (g >= NGRP2) break;

        const float4* rp0 = (const float4*)(reps + (size_t)(g * 128 + ln) * DK);
        const float4* rp1 = rp0 + 64 * (DK / 4);   // row + 64

        float4 a0[8], a1[8];
        #pragma unroll
        for (int q = 0; q < 8; q++) {
            a0[q] = make_float4(0.f, 0.f, 0.f, 0.f);
            a1[q] = make_float4(0.f, 0.f, 0.f, 0.f);
        }
        float n0 = 0.f, n1 = 0.f;

        #pragma unroll 1
        for (int c = 0; c < 4; c++) {              // 4 superchunks of 32 k
            // software-pipelined: one float4 pair live + one in flight
            float4 s0 = rp0[c * 8];
            float4 s1 = rp1[c * 8];
            #pragma unroll
            for (int q = 0; q < 8; q++) {
                float4 t0, t1;
                if (q < 7) { t0 = rp0[c * 8 + q + 1]; t1 = rp1[c * 8 + q + 1]; }
                n0 = fmaf(s0.x, s0.x, n0); n0 = fmaf(s0.y, s0.y, n0);
                n0 = fmaf(s0.z, s0.z, n0); n0 = fmaf(s0.w, s0.w, n0);
                n1 = fmaf(s1.x, s1.x, n1); n1 = fmaf(s1.y, s1.y, n1);
                n1 = fmaf(s1.z, s1.z, n1); n1 = fmaf(s1.w, s1.w, n1);
                const float4* pb = sb4 + (c * 32 + q * 4) * 8;   // k-row base
                #pragma unroll
                for (int j = 0; j < 8; j++) {
                    const float4 p0 = pb[j], p1 = pb[j + 8], p2 = pb[j + 16], p3 = pb[j + 24];
                    float4 A = a0[j];
                    FMA4(A, s0)
                    a0[j] = A;
                    float4 B = a1[j];
                    FMA4(B, s1)
                    a1[j] = B;
                }
                if (q < 7) { s0 = t0; s1 = t1; }
            }
        }

        // ---- pass 0: rows g*128 + 0..63 (lane ln's row0 at slab row ln)
        #pragma unroll
        for (int q = 0; q < 8; q++) {
            float4 v = a0[q];
            v.x += n0; v.y += n0; v.z += n0; v.w += n0;
            *(float4*)&wd[ln * 36 + 4 * q] = v;
        }
        asm volatile("s_waitcnt lgkmcnt(0)" ::: "memory");
        {
            const int nb = g * 128;
            #pragma unroll 4
            for (int s = 0; s < 32; s++) {
                const int row = h * 32 + s;
                topk_insert(wd[row * 36 + b], nb + row, d0, d1, d2, d3, d4, i0, i1, i2, i3, i4);
            }
        }
        asm volatile("s_waitcnt lgkmcnt(0)" ::: "memory");

        // ---- pass 1: rows g*128 + 64..127
        #pragma unroll
        for (int q = 0; q < 8; q++) {
            float4 v = a1[q];
            v.x += n1; v.y += n1; v.z += n1; v.w += n1;
            *(float4*)&wd[ln * 36 + 4 * q] = v;
        }
        asm volatile("s_waitcnt lgkmcnt(0)" ::: "memory");
        {
            const int nb = g * 128 + 64;
            #pragma unroll 4
            for (int s = 0; s < 32; s++) {
                const int row = h * 32 + s;
                topk_insert(wd[row * 36 + b], nb + row, d0, d1, d2, d3, d4, i0, i1, i2, i3, i4);
            }
        }
        asm volatile("s_waitcnt lgkmcnt(0)" ::: "memory");
    }

    // ---- block merge: 8 lists (4 waves x 2 halves) per batch row
    __syncthreads();
    float* cD = wdist;                 // 256*5 = 1280 f
    int*   cI = (int*)(wdist + 1280);  // 1280 i
    {
        const int base = t * 5;
        cD[base]     = d0; cI[base]     = i0;
        cD[base + 1] = d1; cI[base + 1] = i1;
        cD[base + 2] = d2; cI[base + 2] = i2;
        cD[base + 3] = d3; cI[base + 3] = i3;
        cD[base + 4] = d4; cI[base + 4] = i4;
    }
    __syncthreads();
    if (t < 32) {
        float e0 = 3.0e38f, e1 = 3.0e38f, e2 = 3.0e38f, e3 = 3.0e38f, e4 = 3.0e38f;
        int   j0 = 0, j1 = 0, j2 = 0, j3 = 0, j4 = 0;
        for (int j = 0; j < 8; j++) {
            const int base = (t + 32 * j) * 5;
            #pragma unroll
            for (int e = 0; e < 5; e++)
                topk_insert(cD[base + e], cI[base + e],
                            e0, e1, e2, e3, e4, j0, j1, j2, j3, j4);
        }
        const int ob = (blk * BATCH + t) * 5;
        pd[ob] = e0; pd[ob + 1] = e1; pd[ob + 2] = e2; pd[ob + 3] = e3; pd[ob + 4] = e4;
        pi[ob] = j0; pi[ob + 1] = j1; pi[ob + 2] = j2; pi[ob + 3] = j3; pi[ob + 4] = j4;
    }
}

// ---------------------------------------------------------------------------
// Kernel 3: merge G partial lists per b, softmax(-dist), gather actions.
// ---------------------------------------------------------------------------
__global__ __launch_bounds__(256) void final_kernel(
    const float* __restrict__ pd, const int* __restrict__ pi,
    const float* __restrict__ brnorm, const float* __restrict__ actions,
    float* __restrict__ out, int G)
{
    __shared__ float lD[256 * 5];
    __shared__ int   lI[256 * 5];
    __shared__ float sD[32 * 5];
    __shared__ int   sI[32 * 5];
    const int b = blockIdx.x, t = threadIdx.x;

    float d0 = 3.0e38f, d1 = 3.0e38f, d2 = 3.0e38f, d3 = 3.0e38f, d4 = 3.0e38f;
    int   i0 = 0, i1 = 0, i2 = 0, i3 = 0, i4 = 0;
    for (int g = t; g < G; g += 256) {
        const int base = (g * BATCH + b) * 5;
        #pragma unroll
        for (int e = 0; e < 5; e++)
            topk_insert(pd[base + e], pi[base + e],
                        d0, d1, d2, d3, d4, i0, i1, i2, i3, i4);
    }
    lD[t * 5] = d0; lD[t * 5 + 1] = d1; lD[t * 5 + 2] = d2; lD[t * 5 + 3] = d3; lD[t * 5 + 4] = d4;
    lI[t * 5] = i0; lI[t * 5 + 1] = i1; lI[t * 5 + 2] = i2; lI[t * 5 + 3] = i3; lI[t * 5 + 4] = i4;
    __syncthreads();
    if (t < 32) {
        d0 = d1 = d2 = d3 = d4 = 3.0e38f; i0 = i1 = i2 = i3 = i4 = 0;
        for (int s = 0; s < 8; s++) {
            const int base = (t * 8 + s) * 5;
            #pragma unroll
            for (int e = 0; e < 5; e++)
                topk_insert(lD[base + e], lI[base + e],
                            d0, d1, d2, d3, d4, i0, i1, i2, i3, i4);
        }
        sD[t * 5] = d0; sD[t * 5 + 1] = d1; sD[t * 5 + 2] = d2; sD[t * 5 + 3] = d3; sD[t * 5 + 4] = d4;
        sI[t * 5] = i0; sI[t * 5 + 1] = i1; sI[t * 5 + 2] = i2; sI[t * 5 + 3] = i3; sI[t * 5 + 4] = i4;
    }
    __syncthreads();
    if (t == 0) {
        d0 = d1 = d2 = d3 = d4 = 3.0e38f; i0 = i1 = i2 = i3 = i4 = 0;
        for (int s = 0; s < 32; s++) {
            const int base = s * 5;
            #pragma unroll
            for (int e = 0; e < 5; e++)
                topk_insert(sD[base + e], sI[base + e],
                            d0, d1, d2, d3, d4, i0, i1, i2, i3, i4);
        }
        const float bn = brnorm[b];
        float dist[5]; int idx[5];
        dist[0] = d0; dist[1] = d1; dist[2] = d2; dist[3] = d3; dist[4] = d4;
        idx[0] = i0; idx[1] = i1; idx[2] = i2; idx[3] = i3; idx[4] = i4;
        float dmin = 3.0e38f;
        #pragma unroll
        for (int e = 0; e < 5; e++) {
            dist[e] = sqrtf(fmaxf(dist[e] + bn, 1e-12f));
            dmin = fminf(dmin, dist[e]);
        }
        float w[5], wsum = 0.f;
        #pragma unroll
        for (int e = 0; e < 5; e++) { w[e] = expf(dmin - dist[e]); wsum += w[e]; }
        const float inv = 1.0f / wsum;
        for (int a = 0; a < ACT; a++) {
            float o = 0.f;
            #pragma unroll
            for (int e = 0; e < 5; e++)
                o = fmaf(w[e], actions[(size_t)idx[e] * ACT + a], o);
            out[b * ACT + a] = o * inv;
        }
    }
}

extern "C" void kernel_launch(void* const* d_in, const int* in_sizes, int n_in,
                              void* d_out, int out_size, void* d_ws, size_t ws_size,
                              hipStream_t stream)
{
    (void)in_sizes; (void)n_in; (void)out_size;
    const float* x       = (const float*)d_in[0];
    const float* W       = (const float*)d_in[1];
    const float* be      = (const float*)d_in[2];
    const float* reps    = (const float*)d_in[3];
    const float* actions = (const float*)d_in[4];
    // d_in[5] = k (always 5; structural)

    float* ws     = (float*)d_ws;
    float* brept  = ws;            // 4096 floats (brep_t[k][b], pre-scaled -2)
    float* brnorm = ws + 4096;     // 32 floats
    int*   cnt    = (int*)(ws + 4128);  // dynamic group counter
    float* pd     = ws + 4160;     // G*32*5 floats

    int G = GBLK;                  // waves grab groups dynamically, any G correct
    {
        const size_t avail_f = ws_size / 4;
        if (avail_f < 4160 + (size_t)G * 320) {
            long fit = ((long)avail_f - 4160) / 320;
            G = (fit < 1) ? 1 : (int)fit;
            if (G > GBLK) G = GBLK;
        }
    }
    int* pi = (int*)(pd + (size_t)G * BATCH * 5);

    encoder_kernel  <<<32, 256, 0, stream>>>(x, W, be, brept, brnorm, cnt);
    dist_topk_kernel<<<G,  256, 0, stream>>>(reps, brept, pd, pi, cnt);
    final_kernel    <<<32, 256, 0, stream>>>(pd, pi, brnorm, actions, (float*)d_out, G);
}